// Round 6
// baseline (15805.562 us; speedup 1.0000x reference)
//
#include <hip/hip_runtime.h>
#include <stdint.h>
#include <stddef.h>

// PowerLawLayer RNN, MI355X persistent-kernel, R10.
//
// R4: 19.7 ms; latency-bound (VALUBusy 11.6%, HBM 1.3%).
// R5: flag-store barrier: NEUTRAL => barrier mechanics not the cost.
// R6: sc0 "XCD-local" exchange: CATASTROPHIC (682 ms). No cross-CU
//     visibility from sc0 on gfx950; agent (sc1->LLC) is the coherence point.
// R7: tagged dataflow (tag<<32|f32 atoms, poll the data itself): 5.78 ms.
// R8: wave-decoupled poll/stage, 1 barrier/step: 5.62 ms (+3% only).
// R9: 9th updater wave + hoisted x load, __launch_bounds__(576,2):
//     REGRESSION 15.4 ms — NOT the structure, the DECLARATION. 9-wave
//     blocks pack (3,2,2,2) waves/SIMD; min-2-waves/EU makes the
//     allocator budget 2 blocks => 6 waves/SIMD => 84 VGPRs < ~130
//     demand => weight arrays spilled; scratch write-back = 24.9 GB
//     (WRITE_SIZE), HBM 1.7 TB/s of pure spill.
// R10: __launch_bounds__(576, 1). Grid==#CUs, so 1 WG/CU is all we need:
//     max 3 waves/SIMD => cap 512/3 ~ 168 VGPR >= demand => no spill.
//     R9's two structural fixes kept verbatim, now properly isolated:
//     (1) dedicated updater wave: producer store-acks drain at ITS
//         barrier arrival, never in a consumer wave's in-order vmcnt
//         queue ahead of the poll loads;
//     (2) x(t+1) load hoisted to step top (register staging, LDS commit
//         after gemv): its round-trip hides under poll+gemv instead of
//         serializing before the barrier's vmcnt(0) drain.
//
// Barrier pairing: compute waves barrier at END of step t; updater wave
// barriers at START of its iteration t. Both execute exactly Tt barriers.
// part[] is double-buffered; compute's step-(t+2) write of part[t&1]
// happens after B(t+1), which the updater only joins after finishing its
// step-t reads. No other cross-wave state.
//
// Workspace: hbuf2[2][64][512] u64 = 524,288 B.

#define Hh   512
#define Tt   1024
#define Bb   64
#define II   256
#define EPSc 0.001f
#define PV   0.2f

typedef unsigned long long u64;

__global__ __launch_bounds__(1024) void plr_init(u64* hbuf2) {
  // buf0: tag 0 == "h(0) ready" (bits = 0.0f). buf1: tag 0 != 1 => stale.
  int idx = blockIdx.x * blockDim.x + threadIdx.x;
  hbuf2[idx] = 0ull;
  hbuf2[idx + 32768] = 0ull;
}

__global__ __launch_bounds__(576, 1)   // 9 waves: 8 compute + 1 updater;
void plr_main(                         // 1 WG/CU (grid==#CUs) => no spill
    const float* __restrict__ x,    // [B, T, I]
    const float* __restrict__ Wih,  // [3H, I]
    const float* __restrict__ Whh,  // [3H, H]
    const float* __restrict__ bias, // [3H]
    float* __restrict__ out,        // [B,T,H] ++ h_f ++ c_f ++ k_f
    u64* hbuf2)                     // [2][B][H] tagged h atoms
{
  __shared__ float h_tile[8 * Hh];        // [bl][j']        16 KB
  __shared__ float x_tile[2 * 8 * II];    // [buf][bl][k]    16 KB
  __shared__ float part[2 * 3264];        // [pb]((gi*8+bl)*8+w)*17+jj 25.5 KB

  const int tid = threadIdx.x;
  const int bid = blockIdx.x;
  const int g   = bid & 7;           // batch group
  const int s   = bid >> 3;          // hidden slice 0..31
  const int j0  = s * 16;
  const int b0  = g * 8;

  if (tid < 512) {
    // ================= compute waves 0..7 =============================
    const int w   = tid >> 6;
    const int l   = tid & 63;
    const int jj  = l & 15;
    const int kc  = (w << 2) | ((l >> 4) & 3);  // k-chunk 0..31
    const int jw  = w << 6;            // h cols [jw, jw+64)
    const int bls = l >> 3;            // staging batch (x)
    const int xk  = (w << 5) + (l & 7) * 4;  // x col window [32w,32w+32)

    // ---- one-time: weights into registers (72 floats/thread) ----------
    float whh[3][16];
    float wih[3][8];
#pragma unroll
    for (int gi = 0; gi < 3; ++gi) {
      const int row = gi * Hh + j0 + jj;
      const float4* ph = (const float4*)(Whh + (size_t)row * Hh + kc * 16);
#pragma unroll
      for (int i = 0; i < 4; ++i) {
        float4 v = ph[i];
        whh[gi][4*i+0] = v.x; whh[gi][4*i+1] = v.y;
        whh[gi][4*i+2] = v.z; whh[gi][4*i+3] = v.w;
      }
      const float4* pi = (const float4*)(Wih + (size_t)row * II + kc * 8);
#pragma unroll
      for (int i = 0; i < 2; ++i) {
        float4 v = pi[i];
        wih[gi][4*i+0] = v.x; wih[gi][4*i+1] = v.y;
        wih[gi][4*i+2] = v.z; wih[gi][4*i+3] = v.w;
      }
    }

    // ---- prologue: stage x(0), wave-private window (no barrier) -------
    *(float4*)(x_tile + bls * II + xk) =
        *(const float4*)(x + ((size_t)(b0 + bls) * Tt + 0) * II + xk);

    bool broken = false;

    for (int t = 0; t < Tt; ++t) {
      // ---- hoisted x(t+1) load: issue now, consume after gemv ---------
      float4 xreg = make_float4(0.f, 0.f, 0.f, 0.f);
      if (t + 1 < Tt)
        xreg = *(const float4*)(x + ((size_t)(b0 + bls) * Tt + (t + 1)) * II + xk);

      // ---- issue tagged h loads: lane l owns col jw+l, 8 batches -------
      const u64* hb = hbuf2 + (size_t)(t & 1) * Bb * Hh + (size_t)b0 * Hh;
      u64 got[8];
#pragma unroll
      for (int i = 0; i < 8; ++i)
        got[i] = __hip_atomic_load(hb + (size_t)i * Hh + jw + l,
                                   __ATOMIC_RELAXED, __HIP_MEMORY_SCOPE_AGENT);

      // ---- overlap: x-part gemv (wave-private x window) ----------------
      const float* xt = x_tile + (t & 1) * 8 * II;
      float xacc[3][8];
#pragma unroll
      for (int bl = 0; bl < 8; ++bl) {
        const float4* x4 = (const float4*)(xt + bl * II) + kc * 2;
        float a0 = 0.f, a1 = 0.f, a2 = 0.f;
#pragma unroll
        for (int i = 0; i < 2; ++i) {
          float4 xv = x4[i];
          a0 = fmaf(wih[0][4*i+0], xv.x, a0); a0 = fmaf(wih[0][4*i+1], xv.y, a0);
          a0 = fmaf(wih[0][4*i+2], xv.z, a0); a0 = fmaf(wih[0][4*i+3], xv.w, a0);
          a1 = fmaf(wih[1][4*i+0], xv.x, a1); a1 = fmaf(wih[1][4*i+1], xv.y, a1);
          a1 = fmaf(wih[1][4*i+2], xv.z, a1); a1 = fmaf(wih[1][4*i+3], xv.w, a1);
          a2 = fmaf(wih[2][4*i+0], xv.x, a2); a2 = fmaf(wih[2][4*i+1], xv.y, a2);
          a2 = fmaf(wih[2][4*i+2], xv.z, a2); a2 = fmaf(wih[2][4*i+3], xv.w, a2);
        }
        xacc[0][bl] = a0; xacc[1][bl] = a1; xacc[2][bl] = a2;
      }

      // ---- retry: wave-local, gated on this wave's 4 producers ---------
      {
        const unsigned want = (unsigned)t;
        int it = 0;
        for (;;) {
          bool ok = true;
#pragma unroll
          for (int i = 0; i < 8; ++i) ok &= ((unsigned)(got[i] >> 32) == want);
          if (__all((int)ok)) break;
          if (++it > (1 << 20)) { broken = true; break; }
          __builtin_amdgcn_s_sleep(1);
#pragma unroll
          for (int i = 0; i < 8; ++i)
            if ((unsigned)(got[i] >> 32) != want)
              got[i] = __hip_atomic_load(hb + (size_t)i * Hh + jw + l,
                                         __ATOMIC_RELAXED,
                                         __HIP_MEMORY_SCOPE_AGENT);
        }
      }

      // ---- fill this wave's h_tile stripe (same-wave, in-order) --------
#pragma unroll
      for (int i = 0; i < 8; ++i)
        h_tile[i * Hh + jw + l] = __uint_as_float((unsigned)got[i]);

      // ---- h-part gemv: reads only cols [jw, jw+64) --------------------
      float* pb = part + (t & 1) * 3264;
#pragma unroll
      for (int pass = 0; pass < 2; ++pass) {
        float acc[3][4];
#pragma unroll
        for (int b4 = 0; b4 < 4; ++b4) {
          const int bl = pass * 4 + b4;
          const float4* h4 = (const float4*)(h_tile + bl * Hh) + kc * 4;
          float a0 = xacc[0][bl], a1 = xacc[1][bl], a2 = xacc[2][bl];
#pragma unroll
          for (int i = 0; i < 4; ++i) {
            float4 hv = h4[i];
            a0 = fmaf(whh[0][4*i+0], hv.x, a0); a0 = fmaf(whh[0][4*i+1], hv.y, a0);
            a0 = fmaf(whh[0][4*i+2], hv.z, a0); a0 = fmaf(whh[0][4*i+3], hv.w, a0);
            a1 = fmaf(whh[1][4*i+0], hv.x, a1); a1 = fmaf(whh[1][4*i+1], hv.y, a1);
            a1 = fmaf(whh[1][4*i+2], hv.z, a1); a1 = fmaf(whh[1][4*i+3], hv.w, a1);
            a2 = fmaf(whh[2][4*i+0], hv.x, a2); a2 = fmaf(whh[2][4*i+1], hv.y, a2);
            a2 = fmaf(whh[2][4*i+2], hv.z, a2); a2 = fmaf(whh[2][4*i+3], hv.w, a2);
          }
          acc[0][b4] = a0; acc[1][b4] = a1; acc[2][b4] = a2;
        }
#pragma unroll
        for (int gi = 0; gi < 3; ++gi)
#pragma unroll
          for (int b4 = 0; b4 < 4; ++b4) {
            float v = acc[gi][b4];
            v += __shfl_xor(v, 16, 64);
            v += __shfl_xor(v, 32, 64);
            if (l < 16)
              pb[((gi * 8 + pass * 4 + b4) * 8 + w) * 17 + jj] = v;
          }
      }

      // ---- commit hoisted x(t+1) to LDS (load long complete) ----------
      if (t + 1 < Tt)
        *(float4*)(x_tile + ((t + 1) & 1) * 8 * II + bls * II + xk) = xreg;

      __syncthreads();  // (B) partials visible to the updater wave
    }
    (void)broken;

  } else {
    // ================= updater wave (wave 8) ==========================
    // lane u: outputs (br0, jr) and (br0+4, jr); never polls, never
    // reads h_tile/x_tile. Its store acks drain at ITS barrier arrival,
    // off the consumer critical path.
    const int u   = tid - 512;
    const int jr  = u & 15;
    const int br0 = u >> 4;            // 0..3
    const float bia0 = bias[0 * Hh + j0 + jr];
    const float bia1 = bias[1 * Hh + j0 + jr];
    const float bia2 = bias[2 * Hh + j0 + jr];
    float c0 = 0.f, k0 = -1.f, c1 = 0.f, k1 = -1.f;

    for (int t = 0; t < Tt; ++t) {
      __syncthreads();  // (B) pairs with compute waves' end-of-step-t

      const float* pb = part + (t & 1) * 3264;
      float s00 = bia0, s01 = bia1, s02 = bia2;
      float s10 = bia0, s11 = bia1, s12 = bia2;
#pragma unroll
      for (int ww = 0; ww < 8; ++ww) {
        s00 += pb[((0 * 8 + br0) * 8 + ww) * 17 + jr];
        s01 += pb[((1 * 8 + br0) * 8 + ww) * 17 + jr];
        s02 += pb[((2 * 8 + br0) * 8 + ww) * 17 + jr];
        s10 += pb[((0 * 8 + br0 + 4) * 8 + ww) * 17 + jr];
        s11 += pb[((1 * 8 + br0 + 4) * 8 + ww) * 17 + jr];
        s12 += pb[((2 * 8 + br0 + 4) * 8 + ww) * 17 + jr];
      }

      const float tf = (float)t;
      // output 0 (batch b0+br0) and output 1 (batch b0+br0+4), ILP x2
      const float r0  = 1.0f / (1.0f + __expf(-s00));
      const float r1  = 1.0f / (1.0f + __expf(-s10));
      const float o0  = 1.0f / (1.0f + __expf(-s01));
      const float o1  = 1.0f / (1.0f + __expf(-s11));
      const float gg0 = 1.0f - 2.0f / (1.0f + __expf(2.0f * s02));
      const float gg1 = 1.0f - 2.0f / (1.0f + __expf(2.0f * s12));
      const float kn0 = r0 * (tf - EPSc) + (1.0f - r0) * k0;
      const float kn1 = r1 * (tf - EPSc) + (1.0f - r1) * k1;
      const float d0  = tf - kn0;
      const float d1  = tf - kn1;
      const float f0  = __expf(PV * __logf((d0 + EPSc) / (d0 + 1.0f)));
      const float f1  = __expf(PV * __logf((d1 + EPSc) / (d1 + 1.0f)));
      const float cn0 = f0 * c0 + (1.0f - f0) * gg0;
      const float cn1 = f1 * c1 + (1.0f - f1) * gg1;
      const float hn0 = o0 * (1.0f - 2.0f / (1.0f + __expf(2.0f * cn0)));
      const float hn1 = o1 * (1.0f - 2.0f / (1.0f + __expf(2.0f * cn1)));
      c0 = cn0; k0 = kn0; c1 = cn1; k1 = kn1;

      // tagged h atoms (data+signal fused), relaxed agent scope
      if (t + 1 < Tt) {
        u64* hp = hbuf2 + (size_t)((t + 1) & 1) * Bb * Hh;
        u64 a0 = ((u64)(unsigned)(t + 1) << 32) | (u64)__float_as_uint(hn0);
        u64 a1 = ((u64)(unsigned)(t + 1) << 32) | (u64)__float_as_uint(hn1);
        __hip_atomic_store(hp + (size_t)(b0 + br0) * Hh + j0 + jr, a0,
                           __ATOMIC_RELAXED, __HIP_MEMORY_SCOPE_AGENT);
        __hip_atomic_store(hp + (size_t)(b0 + br0 + 4) * Hh + j0 + jr, a1,
                           __ATOMIC_RELAXED, __HIP_MEMORY_SCOPE_AGENT);
      }

      // out[] stores (plain, cached; off every critical path)
      const int bA = b0 + br0, bB = b0 + br0 + 4, j = j0 + jr;
      out[((size_t)bA * Tt + t) * Hh + j] = hn0;
      out[((size_t)bB * Tt + t) * Hh + j] = hn1;
      if (t == Tt - 1) {
        const size_t base = (size_t)Bb * Tt * Hh;
        out[base + 0 * Bb * Hh + (size_t)bA * Hh + j] = hn0;  // h_f
        out[base + 1 * Bb * Hh + (size_t)bA * Hh + j] = cn0;  // c_f
        out[base + 2 * Bb * Hh + (size_t)bA * Hh + j] = kn0;  // k_f
        out[base + 0 * Bb * Hh + (size_t)bB * Hh + j] = hn1;
        out[base + 1 * Bb * Hh + (size_t)bB * Hh + j] = cn1;
        out[base + 2 * Bb * Hh + (size_t)bB * Hh + j] = kn1;
      }
    }
  }
}

extern "C" void kernel_launch(void* const* d_in, const int* in_sizes, int n_in,
                              void* d_out, int out_size, void* d_ws, size_t ws_size,
                              hipStream_t stream) {
  const float* x    = (const float*)d_in[0];
  const float* Wih  = (const float*)d_in[1];
  const float* Whh  = (const float*)d_in[2];
  const float* bias = (const float*)d_in[3];
  float* out = (float*)d_out;

  u64* hbuf2 = (u64*)d_ws;  // [2][64][512] u64 = 512 KiB

  plr_init<<<32, 1024, 0, stream>>>(hbuf2);
  plr_main<<<256, 576, 0, stream>>>(x, Wih, Whh, bias, out, hbuf2);
}

// Round 8
// 5657.823 us; speedup vs baseline: 2.7936x; 2.7936x over previous
//
#include <hip/hip_runtime.h>
#include <stdint.h>
#include <stddef.h>

// PowerLawLayer RNN, MI355X persistent-kernel, R12 (= R11 + safe spin).
//
// R4: 19.7 ms; latency-bound (VALUBusy 11.6%, HBM 1.3%).
// R5: flag-store barrier: NEUTRAL => barrier mechanics not the cost.
// R6: sc0 "XCD-local" exchange: CATASTROPHIC (682 ms). No cross-CU
//     visibility from sc0 on gfx950; agent (sc1->LLC) is the coherence point.
// R7: tagged dataflow (tag<<32|f32 atoms, poll the data itself): 5.78 ms.
// R8: wave-decoupled poll/stage, 1 barrier/step, part[] dbuf: 5.62 ms.
// R9/R10: 9th updater wave: DEAD ON ARRIVAL. 9 waves pack (3,2,2,2) per
//     SIMD; allocator budgets arch-VGPRs 256/3 = 84 < ~130 demand =>
//     weight spill => 24.9 GB scratch write-back, 15.8 ms. 8 waves max.
// R11: hot spin + hoisted x load + setprio on updater. BENCH FAILED
//     (container failed twice, no data). Unbounded-rate hot spin from
//     2048 waves is the only risky edit; if dispatch skew (rocprof
//     replay) delays one group, worst case was 1<<20 iter * ~600cy
//     per step before escape.
// R12: same experiment, bounded risk: ADAPTIVE spin - hot for first 48
//     iterations (steady state resolves in a few round-trips, so the
//     DPM/hot-spin theory still gets tested), then s_sleep(1) pacing;
//     give-up bound shrunk 1<<20 -> 1<<18. All else identical to R11:
//     (1) hot-ish spin keeps SCLK up and removes discovery quantization;
//     (2) x(t+1) load hoisted to step top (register-staged; LDS commit
//         after gemv) so its round-trip hides under poll+gemv;
//     (3) s_setprio(1) around the post-barrier updater block (its EW is
//         on the serial chain; 6 other waves are spinning).
//
// Workspace: hbuf2[2][64][512] u64 = 524,288 B.

#define Hh   512
#define Tt   1024
#define Bb   64
#define II   256
#define EPSc 0.001f
#define PV   0.2f

typedef unsigned long long u64;

__global__ __launch_bounds__(1024) void plr_init(u64* hbuf2) {
  // buf0: tag 0 == "h(0) ready" (bits = 0.0f). buf1: tag 0 != 1 => stale.
  int idx = blockIdx.x * blockDim.x + threadIdx.x;
  hbuf2[idx] = 0ull;
  hbuf2[idx + 32768] = 0ull;
}

__global__ __launch_bounds__(512, 2)   // 8 waves, 2/SIMD => 128-VGPR cap,
void plr_main(                         // demand ~120 => no spill (R8-proven)
    const float* __restrict__ x,    // [B, T, I]
    const float* __restrict__ Wih,  // [3H, I]
    const float* __restrict__ Whh,  // [3H, H]
    const float* __restrict__ bias, // [3H]
    float* __restrict__ out,        // [B,T,H] ++ h_f ++ c_f ++ k_f
    u64* hbuf2)                     // [2][B][H] tagged h atoms
{
  __shared__ float h_tile[8 * Hh];        // [bl][j']        16 KB
  __shared__ float x_tile[2 * 8 * II];    // [buf][bl][k]    16 KB
  __shared__ float part[2 * 3264];        // [pb]((gi*8+bl)*8+w)*17+jj 25.5 KB

  const int tid = threadIdx.x;
  const int w   = tid >> 6;          // wave 0..7
  const int l   = tid & 63;
  const int jj  = l & 15;            // weight row within slice
  const int kc  = (w << 2) | ((l >> 4) & 3);  // k-chunk 0..31
  const int bid = blockIdx.x;
  const int g   = bid & 7;           // batch group
  const int s   = bid >> 3;          // hidden slice 0..31
  const int j0  = s * 16;
  const int b0  = g * 8;
  // wave-private windows
  const int jw  = w << 6;            // h cols [jw, jw+64) consumed by wave w
  const int bls = l >> 3;            // staging batch (x)
  const int xk  = (w << 5) + (l & 7) * 4;  // x col window [32w,32w+32)

  // ---- one-time: weights into registers (72 floats/thread) ------------
  float whh[3][16];
  float wih[3][8];
#pragma unroll
  for (int gi = 0; gi < 3; ++gi) {
    const int row = gi * Hh + j0 + jj;
    const float4* ph = (const float4*)(Whh + (size_t)row * Hh + kc * 16);
#pragma unroll
    for (int i = 0; i < 4; ++i) {
      float4 v = ph[i];
      whh[gi][4*i+0] = v.x; whh[gi][4*i+1] = v.y;
      whh[gi][4*i+2] = v.z; whh[gi][4*i+3] = v.w;
    }
    const float4* pi = (const float4*)(Wih + (size_t)row * II + kc * 8);
#pragma unroll
    for (int i = 0; i < 2; ++i) {
      float4 v = pi[i];
      wih[gi][4*i+0] = v.x; wih[gi][4*i+1] = v.y;
      wih[gi][4*i+2] = v.z; wih[gi][4*i+3] = v.w;
    }
  }

  // ---- updater state (threads 0..127: br = tid>>4, jr = tid&15) -------
  float c_st = 0.0f, k_st = -1.0f;
  float bia0 = 0.f, bia1 = 0.f, bia2 = 0.f;
  if (tid < 128) {
    const int jr = tid & 15;
    bia0 = bias[0 * Hh + j0 + jr];
    bia1 = bias[1 * Hh + j0 + jr];
    bia2 = bias[2 * Hh + j0 + jr];
  }

  // ---- prologue: stage x(0), wave-private window (no barrier) ---------
  *(float4*)(x_tile + bls * II + xk) =
      *(const float4*)(x + ((size_t)(b0 + bls) * Tt + 0) * II + xk);

  bool broken = false;  // bounded-spin escape (never taken when co-resident)

  for (int t = 0; t < Tt; ++t) {
    // ---- hoisted x(t+1) load: issue now, commit to LDS after gemv -----
    float4 xreg = make_float4(0.f, 0.f, 0.f, 0.f);
    if (t + 1 < Tt)
      xreg = *(const float4*)(x + ((size_t)(b0 + bls) * Tt + (t + 1)) * II + xk);

    // ---- issue tagged h loads: lane l owns col jw+l, 8 batches ---------
    const u64* hb = hbuf2 + (size_t)(t & 1) * Bb * Hh + (size_t)b0 * Hh;
    u64 got[8];
#pragma unroll
    for (int i = 0; i < 8; ++i)
      got[i] = __hip_atomic_load(hb + (size_t)i * Hh + jw + l,
                                 __ATOMIC_RELAXED, __HIP_MEMORY_SCOPE_AGENT);

    // ---- overlap: x-part gemv (h-independent, wave-private x window) ---
    const float* xt = x_tile + (t & 1) * 8 * II;
    float xacc[3][8];
#pragma unroll
    for (int bl = 0; bl < 8; ++bl) {
      const float4* x4 = (const float4*)(xt + bl * II) + kc * 2;
      float a0 = 0.f, a1 = 0.f, a2 = 0.f;
#pragma unroll
      for (int i = 0; i < 2; ++i) {
        float4 xv = x4[i];
        a0 = fmaf(wih[0][4*i+0], xv.x, a0); a0 = fmaf(wih[0][4*i+1], xv.y, a0);
        a0 = fmaf(wih[0][4*i+2], xv.z, a0); a0 = fmaf(wih[0][4*i+3], xv.w, a0);
        a1 = fmaf(wih[1][4*i+0], xv.x, a1); a1 = fmaf(wih[1][4*i+1], xv.y, a1);
        a1 = fmaf(wih[1][4*i+2], xv.z, a1); a1 = fmaf(wih[1][4*i+3], xv.w, a1);
        a2 = fmaf(wih[2][4*i+0], xv.x, a2); a2 = fmaf(wih[2][4*i+1], xv.y, a2);
        a2 = fmaf(wih[2][4*i+2], xv.z, a2); a2 = fmaf(wih[2][4*i+3], xv.w, a2);
      }
      xacc[0][bl] = a0; xacc[1][bl] = a1; xacc[2][bl] = a2;
    }

    // ---- retry: wave-local adaptive spin (hot first, then paced) -------
    {
      const unsigned want = (unsigned)t;
      int it = 0;
      for (;;) {
        bool ok = true;
#pragma unroll
        for (int i = 0; i < 8; ++i) ok &= ((unsigned)(got[i] >> 32) == want);
        if (__all((int)ok)) break;          // wave-coherent exit
        ++it;
        if (it > (1 << 18)) { broken = true; break; }
        if (it > 48) __builtin_amdgcn_s_sleep(1);  // backoff only if late
#pragma unroll
        for (int i = 0; i < 8; ++i)
          if ((unsigned)(got[i] >> 32) != want)
            got[i] = __hip_atomic_load(hb + (size_t)i * Hh + jw + l,
                                       __ATOMIC_RELAXED,
                                       __HIP_MEMORY_SCOPE_AGENT);
      }
    }

    // ---- fill this wave's h_tile stripe (same-wave, in-order) ----------
#pragma unroll
    for (int i = 0; i < 8; ++i)
      h_tile[i * Hh + jw + l] = __uint_as_float((unsigned)got[i]);

    // ---- h-part gemv: reads only cols [jw, jw+64) => no barrier --------
    float* pb = part + (t & 1) * 3264;
#pragma unroll
    for (int pass = 0; pass < 2; ++pass) {
      float acc[3][4];
#pragma unroll
      for (int b4 = 0; b4 < 4; ++b4) {
        const int bl = pass * 4 + b4;
        const float4* h4 = (const float4*)(h_tile + bl * Hh) + kc * 4;
        float a0 = xacc[0][bl], a1 = xacc[1][bl], a2 = xacc[2][bl];
#pragma unroll
        for (int i = 0; i < 4; ++i) {
          float4 hv = h4[i];
          a0 = fmaf(whh[0][4*i+0], hv.x, a0); a0 = fmaf(whh[0][4*i+1], hv.y, a0);
          a0 = fmaf(whh[0][4*i+2], hv.z, a0); a0 = fmaf(whh[0][4*i+3], hv.w, a0);
          a1 = fmaf(whh[1][4*i+0], hv.x, a1); a1 = fmaf(whh[1][4*i+1], hv.y, a1);
          a1 = fmaf(whh[1][4*i+2], hv.z, a1); a1 = fmaf(whh[1][4*i+3], hv.w, a1);
          a2 = fmaf(whh[2][4*i+0], hv.x, a2); a2 = fmaf(whh[2][4*i+1], hv.y, a2);
          a2 = fmaf(whh[2][4*i+2], hv.z, a2); a2 = fmaf(whh[2][4*i+3], hv.w, a2);
        }
        acc[0][b4] = a0; acc[1][b4] = a1; acc[2][b4] = a2;
      }
      // reduce the 4 kl sub-chunks in-register, one masked store per combo
#pragma unroll
      for (int gi = 0; gi < 3; ++gi)
#pragma unroll
        for (int b4 = 0; b4 < 4; ++b4) {
          float v = acc[gi][b4];
          v += __shfl_xor(v, 16, 64);
          v += __shfl_xor(v, 32, 64);
          if (l < 16)
            pb[((gi * 8 + pass * 4 + b4) * 8 + w) * 17 + jj] = v;
        }
    }

    // ---- commit hoisted x(t+1) to LDS (load long complete) ------------
    if (t + 1 < Tt)
      *(float4*)(x_tile + ((t + 1) & 1) * 8 * II + bls * II + xk) = xreg;

    __syncthreads();  // (B) the ONE barrier: partials visible to updaters

    // ---- reduce + elementwise + tagged h store (threads 0..127) --------
    // Other waves loop immediately: poll(t+1) overlaps this tail.
    if (tid < 128) {
      __builtin_amdgcn_s_setprio(1);   // serial-chain work: win arbitration
      const int jr = tid & 15, br = tid >> 4;
      float s0 = bia0, s1 = bia1, s2 = bia2;
#pragma unroll
      for (int ww = 0; ww < 8; ++ww) {
        s0 += pb[((0 * 8 + br) * 8 + ww) * 17 + jr];
        s1 += pb[((1 * 8 + br) * 8 + ww) * 17 + jr];
        s2 += pb[((2 * 8 + br) * 8 + ww) * 17 + jr];
      }
      const float tf = (float)t;
      const float r  = 1.0f / (1.0f + __expf(-s0));
      const float o  = 1.0f / (1.0f + __expf(-s1));
      const float gg = 1.0f - 2.0f / (1.0f + __expf(2.0f * s2));
      const float kn = r * (tf - EPSc) + (1.0f - r) * k_st;
      const float d  = tf - kn;
      const float f  = __expf(PV * __logf((d + EPSc) / (d + 1.0f)));
      const float cn = f * c_st + (1.0f - f) * gg;
      const float hn = o * (1.0f - 2.0f / (1.0f + __expf(2.0f * cn)));
      c_st = cn; k_st = kn;

      // data+signal fused: one relaxed agent dwordx2
      if (t + 1 < Tt) {
        u64* hp = hbuf2 + (size_t)((t + 1) & 1) * Bb * Hh +
                  (size_t)(b0 + br) * Hh + j0 + jr;
        u64 atom = ((u64)(unsigned)(t + 1) << 32) |
                   (u64)__float_as_uint(hn);
        __hip_atomic_store(hp, atom, __ATOMIC_RELAXED,
                           __HIP_MEMORY_SCOPE_AGENT);
      }

      // out[] store (plain, cached; off every critical path)
      const int b = b0 + br, j = j0 + jr;
      out[((size_t)b * Tt + t) * Hh + j] = hn;
      if (t == Tt - 1) {
        const size_t base = (size_t)Bb * Tt * Hh;
        out[base + 0 * Bb * Hh + (size_t)b * Hh + j] = hn;  // h_f
        out[base + 1 * Bb * Hh + (size_t)b * Hh + j] = cn;  // c_f
        out[base + 2 * Bb * Hh + (size_t)b * Hh + j] = kn;  // k_f
      }
      __builtin_amdgcn_s_setprio(0);
    }
    // no second barrier: part[] is double-buffered; next write to this
    // buffer (step t+2) is ordered after B(t+1), which the updater only
    // reaches after its reads above complete.
  }
  (void)broken;
}

extern "C" void kernel_launch(void* const* d_in, const int* in_sizes, int n_in,
                              void* d_out, int out_size, void* d_ws, size_t ws_size,
                              hipStream_t stream) {
  const float* x    = (const float*)d_in[0];
  const float* Wih  = (const float*)d_in[1];
  const float* Whh  = (const float*)d_in[2];
  const float* bias = (const float*)d_in[3];
  float* out = (float*)d_out;

  u64* hbuf2 = (u64*)d_ws;  // [2][64][512] u64 = 512 KiB

  plr_init<<<32, 1024, 0, stream>>>(hbuf2);
  plr_main<<<256, 512, 0, stream>>>(x, Wih, Whh, bias, out, hbuf2);
}